// Round 10
// baseline (178.087 us; speedup 1.0000x reference)
//
#include <hip/hip_runtime.h>

typedef __bf16 bf16x8 __attribute__((ext_vector_type(8)));
typedef float floatx4 __attribute__((ext_vector_type(4)));

#define XS 136      // LDS row stride in bf16 elements (272 B -> 2-way bank aliasing = free)
#define ROWS 128    // rows per block
#define PADROWS 144 // packed+tile-padded row slots (max ceil(n0/16)*16 + ceil(n1/16)*16)

__device__ __forceinline__ unsigned short f32_bf16(float f) {
    union { float f; unsigned int u; } c; c.f = f;
    return (unsigned short)((c.u + 0x7fffu + ((c.u >> 16) & 1u)) >> 16);  // RNE, finite inputs
}

// w1 -> MFMA B-fragment order, hidden-col mapping h(nt,l15) = l15*32 + nt.
// frag f = (e*32+nt)*4+ks ; lane (quad,l15) holds B[k=quad*8+j][n=l15] = w1[e][h][k]
__global__ __launch_bounds__(256) void prep_w1_frag(const float* __restrict__ w1,
                                                    unsigned short* __restrict__ wbf) {
    int g    = blockIdx.x * 256 + threadIdx.x;   // 64 blocks -> 16384 threads
    int lane = g & 63;
    int frag = g >> 6;                            // 0..255
    int ks   = frag & 3;
    int nt   = (frag >> 2) & 31;
    int e    = frag >> 7;
    int l15  = lane & 15;
    int quad = lane >> 4;
    int h    = l15 * 32 + nt;
    const float* src = w1 + ((e * 512 + h) * 128 + ks * 32 + quad * 8);
    unsigned short* dst = wbf + (long)g * 8;      // 16 B/lane, contiguous per wave
    #pragma unroll
    for (int j = 0; j < 8; ++j) dst[j] = f32_bf16(src[j]);
}

// Round-10 kernel A: routing only, full-GPU parallel, no LDS/barriers.
// EXACT same fp64 arithmetic order as the in-kernel version (bit-identical
// routing decisions): 2 threads/row, 16x4 component order, shfl_xor combine.
// Also warms L3 with x (64 MB fits the 256 MB LLC) for kernel B's staging.
__global__ __launch_bounds__(256) void route_k(const float* __restrict__ x,
                                               const float* __restrict__ protos,
                                               unsigned char* __restrict__ t8) {
    int g   = blockIdx.x * 256 + threadIdx.x;     // 1024 blocks -> 262144 threads
    long r  = g >> 1;
    int sub = g & 1;
    const float* xr = x + r * 128 + sub * 64;
    const float* p0 = protos + sub * 64;
    const float* p1 = protos + 128 + sub * 64;
    double acc = 0.0;
    #pragma unroll
    for (int k = 0; k < 16; ++k) {
        float4 xv = *(const float4*)(xr + k * 4);
        float4 a  = *(const float4*)(p0 + k * 4);
        float4 b  = *(const float4*)(p1 + k * 4);
        acc += ((double)a.x - b.x) * (0.5 * ((double)a.x + b.x) - xv.x);
        acc += ((double)a.y - b.y) * (0.5 * ((double)a.y + b.y) - xv.y);
        acc += ((double)a.z - b.z) * (0.5 * ((double)a.z + b.z) - xv.z);
        acc += ((double)a.w - b.w) * (0.5 * ((double)a.w + b.w) - xv.w);
    }
    acc += __shfl_xor(acc, 1);
    if (sub == 0) t8[r] = (acc > 0.0) ? 1 : 0;    // tie -> expert 0 (numpy argmin)
}

// Round-10 kernel B: r9 verbatim minus the routing phase (reads t8 instead).
// Purpose: per-dispatch rocprof rows = the phase ablation (routing vs rest)
// that three structurally-different ~90us kernels (r0/r7/r9) could not show.
__global__ __launch_bounds__(256, 2) void moe_fused(
    const float* __restrict__ x,
    const unsigned short* __restrict__ wbf,   // fragment-ordered bf16 w1
    const unsigned char* __restrict__ t8,     // [B] expert per row
    const float* __restrict__ b1,             // [2][512]
    const float* __restrict__ w2,             // [2][2][512]
    const float* __restrict__ b2,             // [2][2]
    float* __restrict__ out)                  // [B][2]
{
    __shared__ unsigned short xs[PADROWS * XS];   // 39168 B (packed bf16 rows)
    __shared__ float out_s[2][ROWS][2];           // [slice][row][o] 2048 B
    __shared__ int   t_s[ROWS];                   // 512 B
    __shared__ unsigned short perm_s[2][ROWS];    // packed idx -> source row, 512 B
    __shared__ int   c1w[2];                      // per-wave expert-1 counts, 8 B

    const int tid   = threadIdx.x;
    const int lane  = tid & 63;
    const int wave  = tid >> 6;
    const int quad  = lane >> 4;
    const int l15   = lane & 15;
    const int slice = wave & 1;               // nt-half 0/1
    const int e     = wave >> 1;              // expert
    const long rowbase = (long)blockIdx.x * ROWS;

    // ---- routing table load (replaces in-kernel fp64 routing) ----
    if (tid < ROWS) t_s[tid] = t8[rowbase + tid];
    __syncthreads();

    // ---- pack rows by expert: stable 2-wave ballot prefix (rows 0-63 / 64-127) ----
    unsigned long long m1 = 0;
    int myt = 0;
    if (tid < 128) {
        myt = t_s[tid];
        m1  = __ballot(myt == 1);
        if ((tid & 63) == 0) c1w[tid >> 6] = __popcll(m1);
    }
    __syncthreads();
    if (tid < 128) {
        int w  = tid >> 6;
        int ln = tid & 63;
        unsigned long long lt = (((unsigned long long)1) << ln) - 1;
        int below1 = __popcll(m1 & lt);
        int r1 = (w ? c1w[0] : 0) + below1;
        int r0 = (w ? 64 - c1w[0] : 0) + (ln - below1);
        if (myt) perm_s[1][r1] = (unsigned short)tid;
        else     perm_s[0][r0] = (unsigned short)tid;
    }
    __syncthreads();

    const int n1 = c1w[0] + c1w[1];
    const int n0 = ROWS - n1;
    const int P  = (n0 + 15) & ~15;           // expert-1 packed base (tile-aligned)

    // ---- stage x PERMUTED by destination slot: coalesced 128B-per-rowgroup reads ----
    // slot p < n0 : source row perm_s[0][p] ; P <= p < P+n1 : perm_s[1][p-P] ; else 0
    for (int i = tid; i < PADROWS * 32; i += 256) {
        int p  = i >> 5;
        int c4 = (i & 31) * 4;
        ushort4 pk = {0, 0, 0, 0};
        int src = -1;
        if (p < n0)                    src = perm_s[0][p];
        else if (p >= P && p - P < n1) src = perm_s[1][p - P];
        if (src >= 0) {
            float4 v = *(const float4*)(x + (rowbase + src) * 128 + c4);
            pk.x = f32_bf16(v.x); pk.y = f32_bf16(v.y);
            pk.z = f32_bf16(v.z); pk.w = f32_bf16(v.w);
        }
        *(ushort4*)&xs[p * XS + c4] = pk;
    }
    __syncthreads();

    // ---- per-wave geometry: this expert's packed tiles ----
    const int ne    = e ? n1 : n0;
    const int Te    = __builtin_amdgcn_readfirstlane((ne + 15) >> 4);  // <= 8, scalar
    const int pbase = e ? P : 0;

    // ---- A fragments: up to 8 packed m-tiles x 4 k-steps (guarded pre-read) ----
    // A-operand layout: A[m = lane&15][k = quad*8 + j]
    bf16x8 afrag[8][4];
    #pragma unroll
    for (int mt = 0; mt < 8; ++mt) {
        if (mt < Te) {
            int r = pbase + mt * 16 + l15;
            #pragma unroll
            for (int ks = 0; ks < 4; ++ks)
                afrag[mt][ks] = *(const bf16x8*)&xs[r * XS + ks * 32 + quad * 8];
        }
    }

    float outp[8][4][2] = {};   // [m-tile][reg(row)][o] layer-2 partials

    // ---- main loop: 16 n-tiles (this wave's expert + nt-half), guarded r0 body ----
    const bf16x8* wb8 = (const bf16x8*)wbf + (long)((e * 32 + slice * 16) * 4) * 64 + lane;
    const int    coff = e * 512 + l15 * 32 + slice * 16;
    const float* b1p  = b1 + coff;
    const float* w2ap = w2 + e * 1024 + l15 * 32 + slice * 16;
    const float* w2bp = w2ap + 512;
    for (int nt = 0; nt < 16; ++nt) {
        const bf16x8* wp = wb8 + nt * 256;
        bf16x8 bf0 = wp[0];
        bf16x8 bf1 = wp[64];
        bf16x8 bf2 = wp[128];
        bf16x8 bf3 = wp[192];
        float bb  = b1p[nt];
        float w2a = w2ap[nt];
        float w2b = w2bp[nt];
        #pragma unroll
        for (int mt = 0; mt < 8; ++mt) {
            if (mt < Te) {                    // wave-uniform scalar predicate
                floatx4 c = {bb, bb, bb, bb}; // bias folded into accumulator init
                c = __builtin_amdgcn_mfma_f32_16x16x32_bf16(afrag[mt][0], bf0, c, 0, 0, 0);
                c = __builtin_amdgcn_mfma_f32_16x16x32_bf16(afrag[mt][1], bf1, c, 0, 0, 0);
                c = __builtin_amdgcn_mfma_f32_16x16x32_bf16(afrag[mt][2], bf2, c, 0, 0, 0);
                c = __builtin_amdgcn_mfma_f32_16x16x32_bf16(afrag[mt][3], bf3, c, 0, 0, 0);
                #pragma unroll
                for (int rg = 0; rg < 4; ++rg) {
                    float h = fmaxf(c[rg], 0.0f);
                    outp[mt][rg][0] = fmaf(h, w2a, outp[mt][rg][0]);
                    outp[mt][rg][1] = fmaf(h, w2b, outp[mt][rg][1]);
                }
            }
        }
    }

    // ---- reduce layer-2 partials across 16 column-lanes, scatter via perm ----
    #pragma unroll
    for (int mt = 0; mt < 8; ++mt) {
        if (mt < Te) {
            #pragma unroll
            for (int rg = 0; rg < 4; ++rg) {
                float v0 = outp[mt][rg][0];
                float v1 = outp[mt][rg][1];
                v0 += __shfl_xor(v0, 1);  v1 += __shfl_xor(v1, 1);
                v0 += __shfl_xor(v0, 2);  v1 += __shfl_xor(v1, 2);
                v0 += __shfl_xor(v0, 4);  v1 += __shfl_xor(v1, 4);
                v0 += __shfl_xor(v0, 8);  v1 += __shfl_xor(v1, 8);
                if (l15 == 0) {
                    int p = mt * 16 + quad * 4 + rg;  // C/D: row = quad*4 + reg
                    if (p < ne) {
                        int r = perm_s[e][p];
                        out_s[slice][r][0] = v0;
                        out_s[slice][r][1] = v1;
                    }
                }
            }
        }
    }
    __syncthreads();

    // ---- combine nt-halves, add b2, coalesced store (each row in exactly 1 list) ----
    {
        int r  = tid >> 1;
        int o  = tid & 1;
        int te = t_s[r];
        out[(rowbase + r) * 2 + o] =
            out_s[0][r][o] + out_s[1][r][o] + b2[te * 2 + o];
    }
}

extern "C" void kernel_launch(void* const* d_in, const int* in_sizes, int n_in,
                              void* d_out, int out_size, void* d_ws, size_t ws_size,
                              hipStream_t stream) {
    const float* x      = (const float*)d_in[0];
    const float* w1     = (const float*)d_in[1];
    const float* b1     = (const float*)d_in[2];
    const float* w2     = (const float*)d_in[3];
    const float* b2     = (const float*)d_in[4];
    const float* protos = (const float*)d_in[5];
    float* out = (float*)d_out;
    unsigned short* wbf = (unsigned short*)d_ws;                    // 256 KiB fragments
    unsigned char*  t8  = (unsigned char*)d_ws + 262144;            // 128 KiB routing

    prep_w1_frag<<<dim3(64),   dim3(256), 0, stream>>>(w1, wbf);
    route_k     <<<dim3(1024), dim3(256), 0, stream>>>(x, protos, t8);
    moe_fused   <<<dim3(1024), dim3(256), 0, stream>>>(x, wbf, t8, b1, w2, b2, out);
}